// Round 2
// baseline (42.247 us; speedup 1.0000x reference)
//
#include <hip/hip_runtime.h>

#define RW 25            // floats per row: K + 24 LSP frequencies
#define RPB 256          // rows per block (== threads per block)
#define NV4 (RPB * RW / 4)   // 1600 float4 per block

typedef float f4 __attribute__((ext_vector_type(4)));

__global__ __launch_bounds__(256) void lsp2lpc_kernel(const float* __restrict__ in,
                                                      float* __restrict__ out) {
    __shared__ float sm[RPB * RW];   // 25.6 KB -> 6 blocks/CU
    const long long row0 = (long long)blockIdx.x * RPB;
    const f4* gin4  = (const f4*)(in  + row0 * RW);
    f4*       gout4 = (f4*)(out + row0 * RW);
    f4*       sm4   = (f4*)sm;
    const int tid = threadIdx.x;

    // coalesced vectorized global->LDS staging: 1600 float4 = 6*256 + 64
    #pragma unroll
    for (int i = 0; i < 6; ++i)
        sm4[tid + i * 256] = gin4[tid + i * 256];
    if (tid < 64)
        sm4[tid + 1536] = gin4[tid + 1536];
    __syncthreads();

    // each thread owns one row in LDS (stride 25: conflict-free, gcd(25,32)=1)
    const float* wr = &sm[tid * RW];
    const float K = wr[0];

    // P,Q monic polys in descending powers; leading coeff at index 0.
    float P[RW], Q[RW];
    #pragma unroll
    for (int j = 0; j < RW; ++j) { P[j] = 0.f; Q[j] = 0.f; }
    P[0] = 1.f; Q[0] = 1.f;

    // multiply in one conjugate-pair quadratic (x^2 + a x + 1) at a time:
    //   new[j] = old[j] + a*old[j-1] + old[j-2], iterate j descending (in place).
    // p = wf[1::2] -> w[2],w[4],...,w[24];  q = wf[0::2] -> w[1],w[3],...,w[23]
    #pragma unroll
    for (int k = 0; k < 12; ++k) {
        const float ap = -2.f * __cosf(wr[2 + 2 * k]);
        const float aq = -2.f * __cosf(wr[1 + 2 * k]);
        #pragma unroll
        for (int j = 2 * k + 2; j >= 2; --j) {
            P[j] = P[j] + ap * P[j - 1] + P[j - 2];
            Q[j] = Q[j] + aq * Q[j - 1] + Q[j - 2];
        }
        P[1] += ap * P[0];
        Q[1] += aq * Q[0];
    }

    __syncthreads();   // staging reads done before overwriting LDS (own row only,
                       // but keep a barrier so the wave-level reads above are complete
                       // across the block before any writes land near other rows' data)

    // epilogue: a[i] = 0.5*((P[i+1]-P[i]) + (Q[i+1]+Q[i])) ; out row = [K, a]
    float* orow = &sm[tid * RW];
    orow[0] = K;
    #pragma unroll
    for (int i = 0; i < 24; ++i)
        orow[1 + i] = 0.5f * ((P[i + 1] - P[i]) + (Q[i + 1] + Q[i]));
    __syncthreads();

    // coalesced vectorized LDS->global, non-temporal (output never re-read:
    // keep the input resident in L3 instead)
    #pragma unroll
    for (int i = 0; i < 6; ++i)
        __builtin_nontemporal_store(sm4[tid + i * 256], &gout4[tid + i * 256]);
    if (tid < 64)
        __builtin_nontemporal_store(sm4[tid + 1536], &gout4[tid + 1536]);
}

extern "C" void kernel_launch(void* const* d_in, const int* in_sizes, int n_in,
                              void* d_out, int out_size, void* d_ws, size_t ws_size,
                              hipStream_t stream) {
    const float* in = (const float*)d_in[0];
    float* out = (float*)d_out;
    const int nrows = in_sizes[0] / RW;          // 16*65536 = 1,048,576
    const int nblocks = nrows / RPB;             // 4096 (exactly divisible)
    lsp2lpc_kernel<<<nblocks, RPB, 0, stream>>>(in, out);
}

// Round 3
// 38.034 us; speedup vs baseline: 1.1108x; 1.1108x over previous
//
#include <hip/hip_runtime.h>

#define RW 25            // floats per row: K + 24 LSP frequencies
#define RPB 256          // rows per block (== threads per block)

typedef float f4 __attribute__((ext_vector_type(4)));
typedef float f2 __attribute__((ext_vector_type(2)));

__global__ __launch_bounds__(256) void lsp2lpc_kernel(const float* __restrict__ in,
                                                      float* __restrict__ out) {
    __shared__ float sm[RPB * RW];   // 25.6 KB -> 6 blocks/CU
    const long long row0 = (long long)blockIdx.x * RPB;
    const f4* gin4  = (const f4*)(in  + row0 * RW);
    f4*       gout4 = (f4*)(out + row0 * RW);
    f4*       sm4   = (f4*)sm;
    const int tid = threadIdx.x;

    // coalesced vectorized global->LDS staging: 1600 float4 = 6*256 + 64
    #pragma unroll
    for (int i = 0; i < 6; ++i)
        sm4[tid + i * 256] = gin4[tid + i * 256];
    if (tid < 64)
        sm4[tid + 1536] = gin4[tid + 1536];
    __syncthreads();

    // each thread owns one row in LDS (stride 25: conflict-free, gcd(25,32)=1)
    const float* wr = &sm[tid * RW];
    const float K = wr[0];

    // Hoist all 12 packed coefficient pairs: c[k] = (-2cos w_p, -2cos w_q)
    // p roots come from wf[1::2] = w[2],w[4],..,w[24]; q from wf[0::2] = w[1],..,w[23]
    f2 c[12];
    #pragma unroll
    for (int k = 0; k < 12; ++k) {
        c[k].x = -2.f * __cosf(wr[2 + 2 * k]);
        c[k].y = -2.f * __cosf(wr[1 + 2 * k]);
    }

    // (P[j],Q[j]) packed as float2 -> v_pk_fma_f32, halves main-loop VALU.
    // Monic polys in descending powers; leading coeff at index 0.
    f2 PQ[RW];
    #pragma unroll
    for (int j = 0; j < RW; ++j) PQ[j] = (f2)(0.f);
    PQ[0] = (f2)(1.f);

    // multiply in one conjugate-pair quadratic (x^2 + a x + 1) at a time:
    //   new[j] = old[j] + a*old[j-1] + old[j-2], j descending (in place).
    #pragma unroll
    for (int k = 0; k < 12; ++k) {
        const f2 a = c[k];
        #pragma unroll
        for (int j = 2 * k + 2; j >= 2; --j)
            PQ[j] = PQ[j] + a * PQ[j - 1] + PQ[j - 2];
        PQ[1] = PQ[1] + a * PQ[0];
    }

    // epilogue: a[i] = 0.5*((P[i+1]-P[i]) + (Q[i+1]+Q[i])) ; out row = [K, a]
    // own-row write, own-row read above -> no barrier needed here
    float* orow = &sm[tid * RW];
    orow[0] = K;
    #pragma unroll
    for (int i = 0; i < 24; ++i)
        orow[1 + i] = 0.5f * ((PQ[i + 1].x - PQ[i].x) + (PQ[i + 1].y + PQ[i].y));
    __syncthreads();

    // coalesced vectorized LDS->global, non-temporal (output never re-read)
    #pragma unroll
    for (int i = 0; i < 6; ++i)
        __builtin_nontemporal_store(sm4[tid + i * 256], &gout4[tid + i * 256]);
    if (tid < 64)
        __builtin_nontemporal_store(sm4[tid + 1536], &gout4[tid + 1536]);
}

extern "C" void kernel_launch(void* const* d_in, const int* in_sizes, int n_in,
                              void* d_out, int out_size, void* d_ws, size_t ws_size,
                              hipStream_t stream) {
    const float* in = (const float*)d_in[0];
    float* out = (float*)d_out;
    const int nrows = in_sizes[0] / RW;          // 16*65536 = 1,048,576
    const int nblocks = nrows / RPB;             // 4096 (exactly divisible)
    lsp2lpc_kernel<<<nblocks, RPB, 0, stream>>>(in, out);
}